// Round 1
// baseline (836.085 us; speedup 1.0000x reference)
//
#include <hip/hip_runtime.h>
#include <float.h>

// IQE quasimetric distance, per row:
//   result = measure( union of [x_j, y_j] for j where x_j < y_j )
// computed via the matched-order-statistics identity:
//   a = sort(valid ? x : FLT_MAX), b = sort(valid ? y : FLT_MAX)
//   result = sum_i max(0, b_i - max(a_i, b_{i-1})),  b_{-1} = -inf
// One wave (64 lanes) per row; element e = 2*lane + r, two bitonic-128
// sorts (a and b) run in lockstep via __shfl_xor.

constexpr int D = 128;

__global__ __launch_bounds__(256) void iqe_union_kernel(
    const float* __restrict__ x, const float* __restrict__ y,
    float* __restrict__ out, int B)
{
    const int lane = threadIdx.x & 63;
    const int row  = blockIdx.x * 4 + (threadIdx.x >> 6);
    if (row >= B) return;

    const size_t base = (size_t)row * D + (lane << 1);
    const float2 xv = *reinterpret_cast<const float2*>(x + base);
    const float2 yv = *reinterpret_cast<const float2*>(y + base);

    const bool v0 = xv.x < yv.x;
    const bool v1 = xv.y < yv.y;
    float a0 = v0 ? xv.x : FLT_MAX;
    float b0 = v0 ? yv.x : FLT_MAX;
    float a1 = v1 ? xv.y : FLT_MAX;
    float b1 = v1 ? yv.y : FLT_MAX;

    // Bitonic sort of 128 elements (ascending), element index e = 2*lane + r.
    // Direction bit (e & k) == 0  <=>  (lane & (k>>1)) == 0  (k >= 2).
    #pragma unroll
    for (int k = 2; k <= 128; k <<= 1) {
        const bool up = (lane & (k >> 1)) == 0;
        #pragma unroll
        for (int j = k >> 1; j >= 2; j >>= 1) {
            const int m = j >> 1;                       // lane xor mask (1..32)
            const bool keepMax = (((lane & m) != 0) == up);
            float t;
            t = __shfl_xor(a0, m, 64); a0 = keepMax ? fmaxf(a0, t) : fminf(a0, t);
            t = __shfl_xor(a1, m, 64); a1 = keepMax ? fmaxf(a1, t) : fminf(a1, t);
            t = __shfl_xor(b0, m, 64); b0 = keepMax ? fmaxf(b0, t) : fminf(b0, t);
            t = __shfl_xor(b1, m, 64); b1 = keepMax ? fmaxf(b1, t) : fminf(b1, t);
        }
        {   // j == 1: in-lane compare-exchange between r=0 and r=1
            float lo, hi;
            lo = fminf(a0, a1); hi = fmaxf(a0, a1);
            a0 = up ? lo : hi;  a1 = up ? hi : lo;
            lo = fminf(b0, b1); hi = fmaxf(b0, b1);
            b0 = up ? lo : hi;  b1 = up ? hi : lo;
        }
    }

    // contrib_i = max(0, b_i - max(a_i, b_{i-1}))
    float bprev = __shfl_up(b1, 1, 64);     // lane L gets lane L-1's b1
    if (lane == 0) bprev = -FLT_MAX;        // b_{-1} = -inf
    float c = fmaxf(0.f, b0 - fmaxf(a0, bprev))
            + fmaxf(0.f, b1 - fmaxf(a1, b0));

    // wave-wide sum
    #pragma unroll
    for (int s = 32; s >= 1; s >>= 1) c += __shfl_xor(c, s, 64);
    if (lane == 0) out[row] = c;
}

extern "C" void kernel_launch(void* const* d_in, const int* in_sizes, int n_in,
                              void* d_out, int out_size, void* d_ws, size_t ws_size,
                              hipStream_t stream) {
    const float* x = (const float*)d_in[0];
    const float* y = (const float*)d_in[1];
    float* out = (float*)d_out;
    const int B = in_sizes[0] / D;                  // 524288
    const int blocks = (B + 3) / 4;                 // 4 waves (rows) per block
    iqe_union_kernel<<<blocks, 256, 0, stream>>>(x, y, out, B);
}

// Round 2
// 523.189 us; speedup vs baseline: 1.5981x; 1.5981x over previous
//
#include <hip/hip_runtime.h>
#include <float.h>

// IQE quasimetric:  per row, measure of union of [x_j, y_j] over j with x_j < y_j.
// Identity: a = sort(valid ? x : FLT_MAX), b = sort(valid ? y : FLT_MAX)
//           result = sum_i max(0, b_i - max(a_i, b_{i-1})),  b_{-1} = -inf.
// Layout: 16 lanes per row, 8 elements per lane (e = 8*g + r), 4 rows per wave.
// Bitonic-128: cross-lane substeps use ds_swizzle (xor masks 1,2,4,8, within the
// 16-lane group) + v_med3_f32 with precomputed +-INF selectors (1 VALU per CE).

constexpr int D = 128;
#define INF __builtin_huge_valf()

__device__ inline float med3(float a, float b, float c) {
    return __builtin_amdgcn_fmed3f(a, b, c);
}

template<int M>
__device__ inline float swzx(float v) {   // lane -> lane ^ M  (M in 1..8)
    int i = __builtin_amdgcn_ds_swizzle(__float_as_int(v), (M << 10) | 0x1F);
    return __int_as_float(i);
}

// compile-time-direction in-lane CE
__device__ inline void cea(float& u, float& v) { float lo = fminf(u, v), hi = fmaxf(u, v); u = lo; v = hi; }
__device__ inline void ced(float& u, float& v) { float lo = fminf(u, v), hi = fmaxf(u, v); u = hi; v = lo; }
// per-lane-direction in-lane CE: s = selLo (+-INF); lo slot u gets med3(u,v,s)
__device__ inline void cek(float& u, float& v, float s) {
    float lo = med3(u, v, s), hi = med3(u, v, -s); u = lo; v = hi;
}

// cross-lane substep (xor mask M) applied to both arrays; sel flips sign with
// bit M of the lane id, so partner lanes keep complementary min/max.
template<int M>
__device__ inline void cross2(float (&a)[8], float (&b)[8], float sel) {
    float ta[8], tb[8];
    #pragma unroll
    for (int r = 0; r < 8; r++) { ta[r] = swzx<M>(a[r]); tb[r] = swzx<M>(b[r]); }
    #pragma unroll
    for (int r = 0; r < 8; r++) { a[r] = med3(a[r], ta[r], sel); b[r] = med3(b[r], tb[r], sel); }
}

// in-lane j=4,2,1 substeps with per-lane selector s (stages k>=8)
__device__ inline void inlane3x2(float (&a)[8], float (&b)[8], float s) {
    cek(a[0],a[4],s); cek(a[1],a[5],s); cek(a[2],a[6],s); cek(a[3],a[7],s);
    cek(b[0],b[4],s); cek(b[1],b[5],s); cek(b[2],b[6],s); cek(b[3],b[7],s);
    cek(a[0],a[2],s); cek(a[1],a[3],s); cek(a[4],a[6],s); cek(a[5],a[7],s);
    cek(b[0],b[2],s); cek(b[1],b[3],s); cek(b[4],b[6],s); cek(b[5],b[7],s);
    cek(a[0],a[1],s); cek(a[2],a[3],s); cek(a[4],a[5],s); cek(a[6],a[7],s);
    cek(b[0],b[1],s); cek(b[2],b[3],s); cek(b[4],b[5],s); cek(b[6],b[7],s);
}

__global__ __launch_bounds__(256) void iqe_union_kernel(
    const float* __restrict__ x, const float* __restrict__ y,
    float* __restrict__ out, int B)
{
    const int tid = threadIdx.x;
    const int g   = tid & 15;                       // lane within 16-group
    const int row = blockIdx.x * 16 + (tid >> 4);
    if (row >= B) return;

    const size_t base = (size_t)row * D + g * 8;
    float xs[8], ys[8];
    *reinterpret_cast<float4*>(&xs[0]) = *reinterpret_cast<const float4*>(x + base);
    *reinterpret_cast<float4*>(&xs[4]) = *reinterpret_cast<const float4*>(x + base + 4);
    *reinterpret_cast<float4*>(&ys[0]) = *reinterpret_cast<const float4*>(y + base);
    *reinterpret_cast<float4*>(&ys[4]) = *reinterpret_cast<const float4*>(y + base + 4);

    float a[8], b[8];
    #pragma unroll
    for (int r = 0; r < 8; r++) {
        const bool v = xs[r] < ys[r];
        a[r] = v ? xs[r] : FLT_MAX;
        b[r] = v ? ys[r] : FLT_MAX;
    }

    // per-lane bit signs and +-INF selectors
    const float S1 = (g & 1) ? 1.f : -1.f;
    const float S2 = (g & 2) ? 1.f : -1.f;
    const float S4 = (g & 4) ? 1.f : -1.f;
    const float S8 = (g & 8) ? 1.f : -1.f;
    const float M1 = S1 * INF, M2 = S2 * INF, M4 = S4 * INF, M8 = S8 * INF;
    const float N2 = -M2, N4 = -M4, N8 = -M8;

    // ---- bitonic sort of 128 (element e = 8*g + r), both arrays in lockstep ----
    // k=2 (dir by r bit1)
    cea(a[0],a[1]); ced(a[2],a[3]); cea(a[4],a[5]); ced(a[6],a[7]);
    cea(b[0],b[1]); ced(b[2],b[3]); cea(b[4],b[5]); ced(b[6],b[7]);
    // k=4 (dir by r bit2)
    cea(a[0],a[2]); cea(a[1],a[3]); ced(a[4],a[6]); ced(a[5],a[7]);
    cea(b[0],b[2]); cea(b[1],b[3]); ced(b[4],b[6]); ced(b[5],b[7]);
    cea(a[0],a[1]); cea(a[2],a[3]); ced(a[4],a[5]); ced(a[6],a[7]);
    cea(b[0],b[1]); cea(b[2],b[3]); ced(b[4],b[5]); ced(b[6],b[7]);
    // k=8 (dir by g bit0 -> M1)
    inlane3x2(a, b, M1);
    // k=16 (K=2)
    cross2<1>(a, b, S1 * N2);
    inlane3x2(a, b, M2);
    // k=32 (K=4)
    cross2<2>(a, b, S2 * N4);
    cross2<1>(a, b, S1 * N4);
    inlane3x2(a, b, M4);
    // k=64 (K=8)
    cross2<4>(a, b, S4 * N8);
    cross2<2>(a, b, S2 * N8);
    cross2<1>(a, b, S1 * N8);
    inlane3x2(a, b, M8);
    // k=128 (ascending everywhere; keepMax = bit m -> sel = S_m*INF = M_m)
    cross2<8>(a, b, M8);
    cross2<4>(a, b, M4);
    cross2<2>(a, b, M2);
    cross2<1>(a, b, M1);
    cea(a[0],a[4]); cea(a[1],a[5]); cea(a[2],a[6]); cea(a[3],a[7]);
    cea(b[0],b[4]); cea(b[1],b[5]); cea(b[2],b[6]); cea(b[3],b[7]);
    cea(a[0],a[2]); cea(a[1],a[3]); cea(a[4],a[6]); cea(a[5],a[7]);
    cea(b[0],b[2]); cea(b[1],b[3]); cea(b[4],b[6]); cea(b[5],b[7]);
    cea(a[0],a[1]); cea(a[2],a[3]); cea(a[4],a[5]); cea(a[6],a[7]);
    cea(b[0],b[1]); cea(b[2],b[3]); cea(b[4],b[5]); cea(b[6],b[7]);

    // ---- epilogue: sum max(0, b_e - max(a_e, b_{e-1})) ----
    float prev = __shfl_up(b[7], 1, 64);    // previous lane's b[7]
    if (g == 0) prev = -FLT_MAX;            // b_{-1} = -inf (row boundary)
    float c = 0.f;
    #pragma unroll
    for (int r = 0; r < 8; r++) {
        c += fmaxf(0.f, b[r] - fmaxf(a[r], prev));
        prev = b[r];
    }
    // reduce over the 16-lane group
    c += swzx<1>(c); c += swzx<2>(c); c += swzx<4>(c); c += swzx<8>(c);
    if (g == 0) out[row] = c;
}

extern "C" void kernel_launch(void* const* d_in, const int* in_sizes, int n_in,
                              void* d_out, int out_size, void* d_ws, size_t ws_size,
                              hipStream_t stream) {
    const float* x = (const float*)d_in[0];
    const float* y = (const float*)d_in[1];
    float* out = (float*)d_out;
    const int B = in_sizes[0] / D;            // 524288
    const int blocks = (B + 15) / 16;         // 16 rows per 256-thread block
    iqe_union_kernel<<<blocks, 256, 0, stream>>>(x, y, out, B);
}